// Round 15
// baseline (146.280 us; speedup 1.0000x reference)
//
#include <hip/hip_runtime.h>

// LeakySNN fused: out[b] = b2 + sum_h spksum(x1[b,h]) * W2[h]
// R30 == R29 resubmitted (acquisition timeout at R14; unmeasured).
// R29 = R20 (measured: main 49.9 -> 46.2us, de-phase+setprio confirmed) +
//   occupancy push via half-size accumulator:
//   Per-wave tile 64x64 -> 64x32: acc[4][2] = 32 AGPR (was 64). Block tile
//   128b x 64h, 4 waves (2b x 2h), grid 256x16. Regs ~60V+32A ~= 92 ->
//   5 waves/EU (vs 4 at the old 64V+64A=128 cliff); launch_bounds(256,5)
//   gives a 102-reg budget (no forced spill). Epilogue per wave halves
//   (j-loop 2); L2 fragment traffic +33% (acceptable: 17 of 34.5 TB/s).
//   De-phasing (bar1 pre-GEMM, unsynced epilogue), setprio, b128 search
//   epilogue all preserved. smem 16.9KB = max(64x44 bpl, 128x33 red).
//   Tripwires: V+A > 102 (no occupancy gain) or scratch-spill in
//   WRITE_SIZE -> revert to R20. Flat w/ occupancy up -> pivot to
//   epilogue VALU reduction.
// R13 counters (R20): main 46.2us, MfmaUtil 30%, VALUBusy 54%, Occ 32-34%,
//   HBM 5.3%, VGPR 64, FETCH 18MB, WRITE 1MB. total = main + ~97.8us const.

#define NI 256
#define NH 1024
#define NSTEPS 25
#define BT 128
#define BK 32
#define NTILES (NI / BK)
#define BPS 33        // red row stride (floats); 33 % 32 == 1
#define SROW 44       // breakpoint LDS row stride (floats); 44%32=12, b128-aligned
#define BPW 40        // breakpoint global row width (floats)
#define RW 40         // fallback (R6) LDS row width in halfs

typedef _Float16 half8 __attribute__((ext_vector_type(8)));
typedef _Float16 half4 __attribute__((ext_vector_type(4)));
typedef float float4v __attribute__((ext_vector_type(4)));

__device__ __forceinline__ unsigned f2k(float f) {
    unsigned u = __float_as_uint(f);
    return (u >> 31) ? ~u : (u | 0x80000000u);
}
__device__ __forceinline__ float k2f(unsigned k) {
    unsigned u = (k & 0x80000000u) ? (k & 0x7FFFFFFFu) : ~k;
    return __uint_as_float(u);
}

// 25-step LIF count, exact reference-matching arithmetic (R4/R6).
__device__ __forceinline__ int lif_count(float x1, float beta, float th) {
    float mem = 0.f;
    float spk = (0.f > th) ? 1.f : 0.f;
    int c = 0;
#pragma unroll
    for (int t = 0; t < NSTEPS; t++) {
        mem = fmaf(spk, -th, fmaf(beta, mem, x1));
        spk = (mem > th) ? 1.f : 0.f;
        c += (mem > th);
    }
    return c;
}

__device__ __forceinline__ void split8(const float* src, half8* hi, half8* lo) {
    float4v a = *(const float4v*)src;
    float4v b = *(const float4v*)(src + 4);
#pragma unroll
    for (int e = 0; e < 4; e++) {
        _Float16 h = (_Float16)a[e];
        (*hi)[e] = h;
        (*lo)[e] = (_Float16)(a[e] - (float)h);
        h = (_Float16)b[e];
        (*hi)[e + 4] = h;
        (*lo)[e + 4] = (_Float16)(b[e] - (float)h);
    }
}

__device__ __forceinline__ void round8(const float* src, half8* hi) {
    float4v a = *(const float4v*)src;
    float4v b = *(const float4v*)(src + 4);
#pragma unroll
    for (int e = 0; e < 4; e++) {
        (*hi)[e]     = (_Float16)a[e];
        (*hi)[e + 4] = (_Float16)b[e];
    }
}

// ===================== fast path =====================

// Granule layout (8 halfs = one MFMA k-chunk of one row):
//   G = band*4096 + kt*512 + r8*64 + quad*16 + col
//   holds src[row = band*128 + r8*16 + col][k = kt*32 + quad*8 .. +8]
__global__ __launch_bounds__(256) void snn_prep(
    const float* __restrict__ x, const float* __restrict__ W1,
    const float* __restrict__ thr, const float* __restrict__ betap,
    const float* __restrict__ b1, const float* __restrict__ b2,
    const float* __restrict__ W2,
    float* __restrict__ out, float* __restrict__ bp,
    _Float16* __restrict__ whp, _Float16* __restrict__ wlp,
    _Float16* __restrict__ xhp, int B)
{
    const int tid = threadIdx.x;
    const int XB = B / 8;            // x granules / 256
    int bid = blockIdx.x;

    if (bid < XB) {                  // ---- x round to fp16 (hi only) ----
        const int G = bid * 256 + tid;
        const int band = G >> 12;
        const int rem = G & 4095;
        const int kt = rem >> 9;
        const int rem2 = rem & 511;
        const int r8 = rem2 >> 6, quad = (rem2 >> 4) & 3, col = rem2 & 15;
        const float* src = x + (size_t)(band * 128 + r8 * 16 + col) * NI + kt * 32 + quad * 8;
        half8 hi;
        round8(src, &hi);
        ((half8*)xhp)[G] = hi;
        return;
    }
    bid -= XB;
    if (bid < 128) {                 // ---- W1 exact two-term split ----
        const int G = bid * 256 + tid;   // < 32768
        const int band = G >> 12;
        const int rem = G & 4095;
        const int kt = rem >> 9;
        const int rem2 = rem & 511;
        const int r8 = rem2 >> 6, quad = (rem2 >> 4) & 3, col = rem2 & 15;
        const float* src = W1 + (size_t)(band * 128 + r8 * 16 + col) * NI + kt * 32 + quad * 8;
        half8 hi, lo;
        split8(src, &hi, &lo);
        ((half8*)whp)[G] = hi;
        ((half8*)wlp)[G] = lo;
        return;
    }
    bid -= 128;
    if (bid < 100) {                 // ---- breakpoints, b1 folded in ----
        const int idx = bid * 256 + tid;     // exactly 25600
        const int h = idx / NSTEPS;
        const int k = idx % NSTEPS + 1;      // target count 1..25
        const float th = thr[h];
        const float bj = b1[h];
        float beta = betap[0];
        beta = beta < 0.f ? 0.f : (beta > 1.f ? 1.f : beta);
        // c'_k = smallest float a with lif_count(fl(a + bj)) >= k.
        // Then (acc >= c'_k) <=> count(fl(acc+bj)) >= k: exact (monotone).
        unsigned lo = f2k(-3.0e38f), hi = f2k(3.0e38f);
        float res;
        if (lif_count(k2f(hi) + bj, beta, th) < k) {
            res = 3.0e38f;
        } else if (lif_count(k2f(lo) + bj, beta, th) >= k) {
            res = -3.0e38f;
        } else {
#pragma unroll 1
            for (int it = 0; it < 32; it++) {
                unsigned mid = lo + ((hi - lo) >> 1);
                if (lif_count(k2f(mid) + bj, beta, th) >= k) hi = mid; else lo = mid;
            }
            res = k2f(hi);
        }
        // Layout, row = BPW floats:
        //   s[0..6]=c16,c8,c24,c4,c12,c20,c28(+inf)  s[7]=W2
        //   s[8+i]=c_i, i=0..31 (c_0=-inf, c_26..31=+inf)
        float* s = bp + (size_t)h * BPW;
        s[8 + k] = res;
        if (k == 16) s[0] = res;
        if (k == 8)  s[1] = res;
        if (k == 24) s[2] = res;
        if (k == 4)  s[3] = res;
        if (k == 12) s[4] = res;
        if (k == 20) s[5] = res;
        if (k == 1) {
            s[6] = 3.0e38f;          // c_28 sentinel (only 25 real breakpoints)
            s[7] = W2[h];
            s[8] = -3.0e38f;         // c_0
#pragma unroll
            for (int i = 26; i < 32; i++) s[8 + i] = 3.0e38f;
        }
        return;
    }
    bid -= 100;
    {                                // ---- out init ----
        const int i = bid * 256 + tid;
        if (i < B) out[i] = b2[0];
    }
}

// 4 waves as 2(b) x 2(h); per-wave output 64x32; acc[4][2] = 32 AGPR.
__global__ __launch_bounds__(256, 5) void snn_main_fast(
    const _Float16* __restrict__ xhp, const _Float16* __restrict__ whp,
    const _Float16* __restrict__ wlp, const float* __restrict__ W2,
    const float* __restrict__ bp, float* __restrict__ out)
{
    __shared__ __align__(16) float smem[4224];  // max(64*44 bpl, 128*33 red)

    const int tid  = threadIdx.x;
    const int w    = tid >> 6;
    const int lane = tid & 63;
    const int col  = lane & 15;
    const int quad = lane >> 4;
    const int wbb  = (w >> 1) * 64;     // b-band within 128-row tile
    const int whh  = (w & 1) * 32;      // h-band within 64-col tile
    const int bband = blockIdx.x;
    const int hband = blockIdx.y;       // 16 hbands of 64
    const int b0 = bband * 128;
    const int h0 = hband * 64;
    const int loff = quad * 16 + col;

    const half8* xh = (const half8*)xhp + (size_t)bband * 4096 + (w >> 1) * 256 + loff;
    // W granules: band = hrow/128, r8 = (hrow%128)/16.
    // wave j-fragment rows: h0 + whh + 16j -> r8 = 4*(hband&1) + 2*(w&1) + j
    const size_t wgbase = (size_t)(hband >> 1) * 4096
                        + (size_t)((hband & 1) * 4 + (w & 1) * 2) * 64 + loff;
    const half8* wh = (const half8*)whp + wgbase;
    const half8* wl = (const half8*)wlp + wgbase;

    // stage 64 breakpoint rows; barrier HERE so GEMM->epilogue stays unsynced.
    {
        const float* bpg = bp + (size_t)h0 * BPW;
        for (int f = tid; f < 640; f += 256) {   // 640 float4 = 64 rows x 40
            const int row = f / 10, kq = f % 10;
            const float4v v = *(const float4v*)(bpg + (size_t)f * 4);
            *(float4v*)(smem + row * SROW + kq * 4) = v;
        }
    }
    __syncthreads();   // bar1: bpl ready; no later GEMM sync

    float4v acc[4][2];
#pragma unroll
    for (int i = 0; i < 4; i++)
#pragma unroll
        for (int j = 0; j < 2; j++) acc[i][j] = (float4v){0.f, 0.f, 0.f, 0.f};

    // ---- GEMM: 2-term fragment-direct, compiler-scheduled ----
#pragma unroll 2
    for (int kt = 0; kt < NTILES; kt++) {
        const int gi = kt * 512;
        half8 ah[4], bh[2], bl[2];
#pragma unroll
        for (int i = 0; i < 4; i++) ah[i] = xh[gi + i * 64];
#pragma unroll
        for (int j = 0; j < 2; j++) {
            bh[j] = wh[gi + j * 64];
            bl[j] = wl[gi + j * 64];
        }
        __builtin_amdgcn_s_setprio(1);   // favor MFMA waves vs epilogue waves
#pragma unroll
        for (int j = 0; j < 2; j++)
#pragma unroll
            for (int i = 0; i < 4; i++) {
                acc[i][j] = __builtin_amdgcn_mfma_f32_16x16x32_f16(ah[i], bh[j], acc[i][j], 0, 0, 0);
                acc[i][j] = __builtin_amdgcn_mfma_f32_16x16x32_f16(ah[i], bl[j], acc[i][j], 0, 0, 0);
            }
        __builtin_amdgcn_s_setprio(0);
    }

    // ---- count: levels 1-3 register-resolved, levels 4-5 via ONE b128 ----
    // (no barrier: this wave's own GEMM is done; bpl valid since bar1)
    float part[16];
#pragma unroll
    for (int e = 0; e < 16; e++) part[e] = 0.f;

#pragma unroll
    for (int j = 0; j < 2; j++) {
        const int hl = whh + 16 * j + col;          // [0,64)
        const float* pj = smem + hl * SROW;
        const float4v p0 = *(const float4v*)(pj);
        const float4v p1 = *(const float4v*)(pj + 4);
        const float c16 = p0[0], c8 = p0[1], c24 = p0[2];
        const float c4a = p0[3], c4b = p1[0], c4c = p1[1], c4d = p1[2];
        const float w2 = p1[3];
#pragma unroll
        for (int half = 0; half < 2; half++) {
            float x1[8];
            int mo[8];
#pragma unroll
            for (int e = 0; e < 8; e++) {
                const int ee = e + 8 * half;
                x1[e] = acc[ee >> 2][j][ee & 3];
            }
#pragma unroll
            for (int e = 0; e < 8; e++) {
                const bool g16 = x1[e] >= c16;
                const float cb = g16 ? c24 : c8;
                const bool g8 = x1[e] >= cb;
                const float cc = g16 ? (g8 ? c4d : c4c) : (g8 ? c4b : c4a);
                int m = (g16 ? 16 : 0) + (g8 ? 8 : 0);
                m += (x1[e] >= cc) ? 4 : 0;
                mo[e] = m;
            }
            float4v q[8];
#pragma unroll
            for (int e = 0; e < 8; e++)
                q[e] = *(const float4v*)(pj + 8 + mo[e]);
#pragma unroll
            for (int e = 0; e < 8; e++) {
                int m = mo[e];
                m += (x1[e] >= q[e][1]) ? 1 : 0;
                m += (x1[e] >= q[e][2]) ? 1 : 0;
                m += (x1[e] >= q[e][3]) ? 1 : 0;
                part[e + 8 * half] = fmaf((float)m, w2, part[e + 8 * half]);
            }
        }
    }

    // ---- block reduction, one atomic per b-row ----
    __syncthreads();                   // bar2: all bpl reads done before red[]
    float* red = smem;                 // 128 x 33
#pragma unroll
    for (int e = 0; e < 16; e++) {
        const int row = wbb + 16 * (e >> 2) + 4 * quad + (e & 3);
        red[row * BPS + (w & 1) * 16 + col] = part[e];
    }
    __syncthreads();                   // bar3
    if (tid < 128) {
        float s = 0.f;
#pragma unroll
        for (int c2 = 0; c2 < 32; c2++) s += red[tid * BPS + c2];
        atomicAdd(&out[b0 + tid], s);
    }
}

// ===================== fallback path (R6-style, ws too small) =====================

__global__ __launch_bounds__(256) void snn_prep_small(
    const float* __restrict__ thr, const float* __restrict__ betap,
    const float* __restrict__ b2, float* __restrict__ out,
    float* __restrict__ bp, int B)
{
    const int tid = threadIdx.x;
    int bid = blockIdx.x;
    if (bid < 100) {
        const int idx = bid * 256 + tid;
        const int h = idx / NSTEPS;
        const int k = idx % NSTEPS + 1;
        const float th = thr[h];
        float beta = betap[0];
        beta = beta < 0.f ? 0.f : (beta > 1.f ? 1.f : beta);
        unsigned lo = f2k(-3.0e38f), hi = f2k(3.0e38f);
        float res;
        if (lif_count(k2f(hi), beta, th) < k) res = 3.0e38f;
        else if (lif_count(k2f(lo), beta, th) >= k) res = -3.0e38f;
        else {
#pragma unroll 1
            for (int it = 0; it < 32; it++) {
                unsigned mid = lo + ((hi - lo) >> 1);
                if (lif_count(k2f(mid), beta, th) >= k) hi = mid; else lo = mid;
            }
            res = k2f(hi);
        }
        bp[(k - 1) * NH + h] = res;
        return;
    }
    bid -= 100;
    const int i = bid * 256 + tid;
    if (i < B) out[i] = b2[0];
}

__global__ __launch_bounds__(256, 3) void snn_main_fb(
    const float* __restrict__ x, const float* __restrict__ W1,
    const float* __restrict__ b1, const float* __restrict__ W2,
    const float* __restrict__ bp, float* __restrict__ out)
{
    __shared__ __align__(16) _Float16 lds[4 * BT * RW];
    _Float16* xh = lds;
    _Float16* xl = lds + BT * RW;
    _Float16* wh = lds + 2 * BT * RW;
    _Float16* wl = lds + 3 * BT * RW;

    const int tid  = threadIdx.x;
    const int w    = tid >> 6;
    const int lane = tid & 63;
    const int col  = lane & 15;
    const int quad = lane >> 4;
    const int wbb  = (w >> 1) * 64;
    const int whh  = (w & 1) * 64;
    const int b0 = blockIdx.x * BT;
    const int h0 = blockIdx.y * BT;

    float4v acc[4][4];
#pragma unroll
    for (int i = 0; i < 4; i++)
#pragma unroll
        for (int j = 0; j < 4; j++) acc[i][j] = (float4v){0.f, 0.f, 0.f, 0.f};

    const int r0 = tid >> 3;
    const int c4 = tid & 7;
    const float* xrow = x + (size_t)(b0 + r0) * NI + 4 * c4;
    const float* wrow = W1 + (size_t)(h0 + r0) * NI + 4 * c4;

    for (int kt = 0; kt < NTILES; kt++) {
        const int ko = kt * BK;
        float4v vx[4], vw[4];
#pragma unroll
        for (int p = 0; p < 4; p++) {
            vx[p] = *(const float4v*)(xrow + (size_t)(32 * p) * NI + ko);
            vw[p] = *(const float4v*)(wrow + (size_t)(32 * p) * NI + ko);
        }
        __syncthreads();
#pragma unroll
        for (int p = 0; p < 4; p++) {
            const int row = r0 + 32 * p;
            half4 hx, lx, hw, lw;
#pragma unroll
            for (int q = 0; q < 4; q++) {
                float v = vx[p][q];
                _Float16 h = (_Float16)v;
                hx[q] = h;
                lx[q] = (_Float16)(v - (float)h);
                v = vw[p][q];
                h = (_Float16)v;
                hw[q] = h;
                lw[q] = (_Float16)(v - (float)h);
            }
            *(half4*)&xh[row * RW + 4 * c4] = hx;
            *(half4*)&xl[row * RW + 4 * c4] = lx;
            *(half4*)&wh[row * RW + 4 * c4] = hw;
            *(half4*)&wl[row * RW + 4 * c4] = lw;
        }
        __syncthreads();

        half8 ah[4], al[4];
#pragma unroll
        for (int i = 0; i < 4; i++) {
            ah[i] = *(const half8*)&xh[(wbb + 16 * i + col) * RW + 8 * quad];
            al[i] = *(const half8*)&xl[(wbb + 16 * i + col) * RW + 8 * quad];
        }
#pragma unroll
        for (int j = 0; j < 4; j++) {
            half8 bh = *(const half8*)&wh[(whh + 16 * j + col) * RW + 8 * quad];
            half8 bl = *(const half8*)&wl[(whh + 16 * j + col) * RW + 8 * quad];
#pragma unroll
            for (int i = 0; i < 4; i++) {
                acc[i][j] = __builtin_amdgcn_mfma_f32_16x16x32_f16(ah[i], bh, acc[i][j], 0, 0, 0);
                acc[i][j] = __builtin_amdgcn_mfma_f32_16x16x32_f16(ah[i], bl, acc[i][j], 0, 0, 0);
                acc[i][j] = __builtin_amdgcn_mfma_f32_16x16x32_f16(al[i], bh, acc[i][j], 0, 0, 0);
            }
        }
    }

    __syncthreads();
    float* bpl = (float*)lds;
    for (int n = tid; n < NSTEPS * 128; n += 256)
        bpl[n] = bp[(n >> 7) * NH + h0 + (n & 127)];
    __syncthreads();

    float part[16];
#pragma unroll
    for (int e = 0; e < 16; e++) part[e] = 0.f;
#pragma unroll
    for (int j = 0; j < 4; j++) {
        const int hl = whh + 16 * j + col;
        const int h = h0 + hl;
        const float w2 = W2[h];
        const float bj = b1[h];
        float x1[16];
        int cnt[16];
#pragma unroll
        for (int e = 0; e < 16; e++) {
            x1[e] = acc[e >> 2][j][e & 3] + bj;
            cnt[e] = 0;
        }
#pragma unroll
        for (int k = 0; k < NSTEPS; k++) {
            const float c = bpl[k * 128 + hl];
#pragma unroll
            for (int e = 0; e < 16; e++) cnt[e] += (x1[e] >= c) ? 1 : 0;
        }
#pragma unroll
        for (int e = 0; e < 16; e++)
            part[e] = fmaf((float)cnt[e], w2, part[e]);
    }

    __syncthreads();
    float* red = (float*)lds;
#pragma unroll
    for (int e = 0; e < 16; e++) {
        const int row = wbb + 16 * (e >> 2) + 4 * quad + (e & 3);
        red[row * 33 + (w & 1) * 16 + col] = part[e];
    }
    __syncthreads();
    if (tid < BT) {
        float s = 0.f;
#pragma unroll
        for (int c = 0; c < 32; c++) s += red[tid * 33 + c];
        atomicAdd(&out[b0 + tid], s);
    }
}

extern "C" void kernel_launch(void* const* d_in, const int* in_sizes, int n_in,
                              void* d_out, int out_size, void* d_ws, size_t ws_size,
                              hipStream_t stream) {
    const float* x    = (const float*)d_in[0];
    const float* W1   = (const float*)d_in[1];
    const float* b1   = (const float*)d_in[2];
    const float* W2   = (const float*)d_in[3];
    const float* b2   = (const float*)d_in[4];
    const float* beta = (const float*)d_in[5];
    const float* thr  = (const float*)d_in[6];
    float* out = (float*)d_out;

    const int B = in_sizes[0] / NI;  // 32768

    // ws layout: bp (NH*BPW floats) | wh | wl | xh
    char* ws = (char*)d_ws;
    float*     bp  = (float*)ws;
    size_t off = (size_t)NH * BPW * 4;               // 163840
    _Float16* whp = (_Float16*)(ws + off);  off += (size_t)NH * NI * 2;
    _Float16* wlp = (_Float16*)(ws + off);  off += (size_t)NH * NI * 2;
    _Float16* xhp = (_Float16*)(ws + off);  off += (size_t)B * NI * 2;
    const size_t ws_need = off;

    if (ws_size >= ws_need) {
        const int nblk = B / 8 + 128 + 100 + (B + 255) / 256;
        snn_prep<<<nblk, 256, 0, stream>>>(x, W1, thr, beta, b1, b2, W2, out,
                                           bp, whp, wlp, xhp, B);
        dim3 grid(B / 128, NH / 64);
        snn_main_fast<<<grid, 256, 0, stream>>>(xhp, whp, wlp, W2, bp, out);
    } else {
        snn_prep_small<<<100 + (B + 255) / 256, 256, 0, stream>>>(thr, beta, b2, out, bp, B);
        dim3 grid(B / BT, NH / BT);
        snn_main_fb<<<grid, 256, 0, stream>>>(x, W1, b1, W2, bp, out);
    }
}

// Round 16
// 140.878 us; speedup vs baseline: 1.0383x; 1.0383x over previous
//
#include <hip/hip_runtime.h>

// LeakySNN fused: out[b] = b2 + sum_h spksum(x1[b,h]) * W2[h]
// R31 == R20 reverted (R29/R30 measured 52.0us: tripwire fired).
// R29 post-mortem: half-acc (64x32/wave) raised occupancy 32->42% but
//   REGRESSED main 46.2->52.0. Loads/MFMA per kt went 12/32 -> 8/16; the
//   80cyc MFMA block no longer covers ~200cyc L2 latency -> stalls beat
//   the TLP gain. Lesson: per-wave load ratio dominates occupancy here.
//   64x64/wave (64 AGPR + 64 VGPR = exactly the 128 cliff) is the tile
//   optimum; LDS-dedup of fragments needs K-loop barriers (undoes R20's
//   de-phasing win); A-tile L2 locality already optimal (same-A blocks
//   share an XCD: 256*by % 8 == 0).
// R20 (MEASURED BEST: main 46.2us, total 144.0) = R18 + barrier
//   restructure: bpl staged BEFORE K-loop, barrier after staging only ->
//   GEMM->epilogue unsynced, block's 4 waves de-phase (MFMA/VMEM vs
//   VALU/LDS roles) + s_setprio(1) around MFMA cluster (role-split makes
//   priority arbitration meaningful). Measured: MfmaUtil 27->30,
//   VALUBusy 48->54, VGPR 64, no spill.
// R13 counters (R20): main 46.2us, MfmaUtil 30%, VALUBusy 54%, Occ 32-34%,
//   HBM 5.3%, VGPR 64, FETCH 18MB, WRITE 1MB. total = main + ~97.8us const.

#define NI 256
#define NH 1024
#define NSTEPS 25
#define BT 128
#define BK 32
#define NTILES (NI / BK)
#define BPS 33        // red row stride (floats); 33 % 32 == 1
#define SROW 44       // breakpoint LDS row stride (floats); 44%32=12, b128-aligned
#define BPW 40        // breakpoint global row width (floats)
#define RW 40         // fallback (R6) LDS row width in halfs

typedef _Float16 half8 __attribute__((ext_vector_type(8)));
typedef _Float16 half4 __attribute__((ext_vector_type(4)));
typedef float float4v __attribute__((ext_vector_type(4)));

__device__ __forceinline__ unsigned f2k(float f) {
    unsigned u = __float_as_uint(f);
    return (u >> 31) ? ~u : (u | 0x80000000u);
}
__device__ __forceinline__ float k2f(unsigned k) {
    unsigned u = (k & 0x80000000u) ? (k & 0x7FFFFFFFu) : ~k;
    return __uint_as_float(u);
}

// 25-step LIF count, exact reference-matching arithmetic (R4/R6).
__device__ __forceinline__ int lif_count(float x1, float beta, float th) {
    float mem = 0.f;
    float spk = (0.f > th) ? 1.f : 0.f;
    int c = 0;
#pragma unroll
    for (int t = 0; t < NSTEPS; t++) {
        mem = fmaf(spk, -th, fmaf(beta, mem, x1));
        spk = (mem > th) ? 1.f : 0.f;
        c += (mem > th);
    }
    return c;
}

__device__ __forceinline__ void split8(const float* src, half8* hi, half8* lo) {
    float4v a = *(const float4v*)src;
    float4v b = *(const float4v*)(src + 4);
#pragma unroll
    for (int e = 0; e < 4; e++) {
        _Float16 h = (_Float16)a[e];
        (*hi)[e] = h;
        (*lo)[e] = (_Float16)(a[e] - (float)h);
        h = (_Float16)b[e];
        (*hi)[e + 4] = h;
        (*lo)[e + 4] = (_Float16)(b[e] - (float)h);
    }
}

__device__ __forceinline__ void round8(const float* src, half8* hi) {
    float4v a = *(const float4v*)src;
    float4v b = *(const float4v*)(src + 4);
#pragma unroll
    for (int e = 0; e < 4; e++) {
        (*hi)[e]     = (_Float16)a[e];
        (*hi)[e + 4] = (_Float16)b[e];
    }
}

// ===================== fast path =====================

// Granule layout (8 halfs = one MFMA k-chunk of one row):
//   G = band*4096 + kt*512 + r8*64 + quad*16 + col
//   holds src[row = band*128 + r8*16 + col][k = kt*32 + quad*8 .. +8]
__global__ __launch_bounds__(256) void snn_prep(
    const float* __restrict__ x, const float* __restrict__ W1,
    const float* __restrict__ thr, const float* __restrict__ betap,
    const float* __restrict__ b1, const float* __restrict__ b2,
    const float* __restrict__ W2,
    float* __restrict__ out, float* __restrict__ bp,
    _Float16* __restrict__ whp, _Float16* __restrict__ wlp,
    _Float16* __restrict__ xhp, int B)
{
    const int tid = threadIdx.x;
    const int XB = B / 8;            // x granules / 256
    int bid = blockIdx.x;

    if (bid < XB) {                  // ---- x round to fp16 (hi only) ----
        const int G = bid * 256 + tid;
        const int band = G >> 12;
        const int rem = G & 4095;
        const int kt = rem >> 9;
        const int rem2 = rem & 511;
        const int r8 = rem2 >> 6, quad = (rem2 >> 4) & 3, col = rem2 & 15;
        const float* src = x + (size_t)(band * 128 + r8 * 16 + col) * NI + kt * 32 + quad * 8;
        half8 hi;
        round8(src, &hi);
        ((half8*)xhp)[G] = hi;
        return;
    }
    bid -= XB;
    if (bid < 128) {                 // ---- W1 exact two-term split ----
        const int G = bid * 256 + tid;   // < 32768
        const int band = G >> 12;
        const int rem = G & 4095;
        const int kt = rem >> 9;
        const int rem2 = rem & 511;
        const int r8 = rem2 >> 6, quad = (rem2 >> 4) & 3, col = rem2 & 15;
        const float* src = W1 + (size_t)(band * 128 + r8 * 16 + col) * NI + kt * 32 + quad * 8;
        half8 hi, lo;
        split8(src, &hi, &lo);
        ((half8*)whp)[G] = hi;
        ((half8*)wlp)[G] = lo;
        return;
    }
    bid -= 128;
    if (bid < 100) {                 // ---- breakpoints, b1 folded in ----
        const int idx = bid * 256 + tid;     // exactly 25600
        const int h = idx / NSTEPS;
        const int k = idx % NSTEPS + 1;      // target count 1..25
        const float th = thr[h];
        const float bj = b1[h];
        float beta = betap[0];
        beta = beta < 0.f ? 0.f : (beta > 1.f ? 1.f : beta);
        // c'_k = smallest float a with lif_count(fl(a + bj)) >= k.
        // Then (acc >= c'_k) <=> count(fl(acc+bj)) >= k: exact (monotone).
        unsigned lo = f2k(-3.0e38f), hi = f2k(3.0e38f);
        float res;
        if (lif_count(k2f(hi) + bj, beta, th) < k) {
            res = 3.0e38f;
        } else if (lif_count(k2f(lo) + bj, beta, th) >= k) {
            res = -3.0e38f;
        } else {
#pragma unroll 1
            for (int it = 0; it < 32; it++) {
                unsigned mid = lo + ((hi - lo) >> 1);
                if (lif_count(k2f(mid) + bj, beta, th) >= k) hi = mid; else lo = mid;
            }
            res = k2f(hi);
        }
        // Layout, row = BPW floats:
        //   s[0..6]=c16,c8,c24,c4,c12,c20,c28(+inf)  s[7]=W2
        //   s[8+i]=c_i, i=0..31 (c_0=-inf, c_26..31=+inf)
        float* s = bp + (size_t)h * BPW;
        s[8 + k] = res;
        if (k == 16) s[0] = res;
        if (k == 8)  s[1] = res;
        if (k == 24) s[2] = res;
        if (k == 4)  s[3] = res;
        if (k == 12) s[4] = res;
        if (k == 20) s[5] = res;
        if (k == 1) {
            s[6] = 3.0e38f;          // c_28 sentinel (only 25 real breakpoints)
            s[7] = W2[h];
            s[8] = -3.0e38f;         // c_0
#pragma unroll
            for (int i = 26; i < 32; i++) s[8 + i] = 3.0e38f;
        }
        return;
    }
    bid -= 100;
    {                                // ---- out init ----
        const int i = bid * 256 + tid;
        if (i < B) out[i] = b2[0];
    }
}

__global__ __launch_bounds__(256, 4) void snn_main_fast(
    const _Float16* __restrict__ xhp, const _Float16* __restrict__ whp,
    const _Float16* __restrict__ wlp, const float* __restrict__ W2,
    const float* __restrict__ bp, float* __restrict__ out)
{
    __shared__ __align__(16) float smem[128 * SROW];  // 22.5 KB: bpl, later red

    const int tid  = threadIdx.x;
    const int w    = tid >> 6;
    const int lane = tid & 63;
    const int col  = lane & 15;
    const int quad = lane >> 4;
    const int wbb  = (w >> 1) * 64;
    const int whh  = (w & 1) * 64;
    const int bband = blockIdx.x;
    const int hband = blockIdx.y;
    const int b0 = bband * BT;
    const int h0 = hband * BT;
    const int loff = quad * 16 + col;

    const half8* xh = (const half8*)xhp + (size_t)bband * 4096 + (w >> 1) * 256 + loff;
    const half8* wh = (const half8*)whp + (size_t)hband * 4096 + (w & 1) * 256 + loff;
    const half8* wl = (const half8*)wlp + (size_t)hband * 4096 + (w & 1) * 256 + loff;

    // stage breakpoint rows; barrier HERE (not after GEMM) so the
    // GEMM->epilogue transition is unsynced and waves de-phase.
    {
        const float* bpg = bp + (size_t)h0 * BPW;
#pragma unroll
        for (int r = 0; r < 5; r++) {
            const int f = tid + 256 * r;          // 1280 float4s = 128 rows x 40
            const int row = f / 10, kq = f % 10;
            const float4v v = *(const float4v*)(bpg + (size_t)f * 4);
            *(float4v*)(smem + row * SROW + kq * 4) = v;
        }
    }
    __syncthreads();   // bar1: bpl ready for everyone; no later GEMM sync

    float4v acc[4][4];
#pragma unroll
    for (int i = 0; i < 4; i++)
#pragma unroll
        for (int j = 0; j < 4; j++) acc[i][j] = (float4v){0.f, 0.f, 0.f, 0.f};

    // ---- GEMM: 2-term fragment-direct, compiler-scheduled ----
#pragma unroll 2
    for (int kt = 0; kt < NTILES; kt++) {
        const int gi = kt * 512;
        half8 ah[4], bh[4], bl[4];
#pragma unroll
        for (int i = 0; i < 4; i++) ah[i] = xh[gi + i * 64];
#pragma unroll
        for (int j = 0; j < 4; j++) {
            bh[j] = wh[gi + j * 64];
            bl[j] = wl[gi + j * 64];
        }
        __builtin_amdgcn_s_setprio(1);   // favor MFMA waves vs epilogue waves
#pragma unroll
        for (int j = 0; j < 4; j++)
#pragma unroll
            for (int i = 0; i < 4; i++) {
                acc[i][j] = __builtin_amdgcn_mfma_f32_16x16x32_f16(ah[i], bh[j], acc[i][j], 0, 0, 0);
                acc[i][j] = __builtin_amdgcn_mfma_f32_16x16x32_f16(ah[i], bl[j], acc[i][j], 0, 0, 0);
            }
        __builtin_amdgcn_s_setprio(0);
    }

    // ---- count: levels 1-3 register-resolved, levels 4-5 via ONE b128 ----
    // (no barrier: this wave's own GEMM is done; bpl valid since bar1)
    // m = max{k : x1 >= c_k}. After m3 (mult of 4), q = c_{m3..m3+3} in one
    // aligned ds_read_b128; sorted c => m = m3 + sum_{i=1..3} [x1 >= q[i]].
    float part[16];
#pragma unroll
    for (int e = 0; e < 16; e++) part[e] = 0.f;

#pragma unroll
    for (int j = 0; j < 4; j++) {
        const int hl = whh + 16 * j + col;
        const float* pj = smem + hl * SROW;
        const float4v p0 = *(const float4v*)(pj);
        const float4v p1 = *(const float4v*)(pj + 4);
        const float c16 = p0[0], c8 = p0[1], c24 = p0[2];
        const float c4a = p0[3], c4b = p1[0], c4c = p1[1], c4d = p1[2];
        const float w2 = p1[3];
#pragma unroll
        for (int half = 0; half < 2; half++) {
            float x1[8];
            int mo[8];
#pragma unroll
            for (int e = 0; e < 8; e++) {
                const int ee = e + 8 * half;
                x1[e] = acc[ee >> 2][j][ee & 3];
            }
#pragma unroll
            for (int e = 0; e < 8; e++) {
                const bool g16 = x1[e] >= c16;
                const float cb = g16 ? c24 : c8;
                const bool g8 = x1[e] >= cb;
                const float cc = g16 ? (g8 ? c4d : c4c) : (g8 ? c4b : c4a);
                int m = (g16 ? 16 : 0) + (g8 ? 8 : 0);
                m += (x1[e] >= cc) ? 4 : 0;
                mo[e] = m;
            }
            float4v q[8];
#pragma unroll
            for (int e = 0; e < 8; e++)
                q[e] = *(const float4v*)(pj + 8 + mo[e]);
#pragma unroll
            for (int e = 0; e < 8; e++) {
                int m = mo[e];
                m += (x1[e] >= q[e][1]) ? 1 : 0;
                m += (x1[e] >= q[e][2]) ? 1 : 0;
                m += (x1[e] >= q[e][3]) ? 1 : 0;
                part[e + 8 * half] = fmaf((float)m, w2, part[e + 8 * half]);
            }
        }
    }

    // ---- block reduction, one atomic per b-row ----
    __syncthreads();                   // bar2: all bpl reads done before red[]
    float* red = smem;                 // 128 x 33
#pragma unroll
    for (int e = 0; e < 16; e++) {
        const int row = wbb + 16 * (e >> 2) + 4 * quad + (e & 3);
        red[row * BPS + (w & 1) * 16 + col] = part[e];
    }
    __syncthreads();                   // bar3
    if (tid < BT) {
        float s = 0.f;
#pragma unroll
        for (int c2 = 0; c2 < 32; c2++) s += red[tid * BPS + c2];
        atomicAdd(&out[b0 + tid], s);
    }
}

// ===================== fallback path (R6-style, ws too small) =====================

__global__ __launch_bounds__(256) void snn_prep_small(
    const float* __restrict__ thr, const float* __restrict__ betap,
    const float* __restrict__ b2, float* __restrict__ out,
    float* __restrict__ bp, int B)
{
    const int tid = threadIdx.x;
    int bid = blockIdx.x;
    if (bid < 100) {
        const int idx = bid * 256 + tid;
        const int h = idx / NSTEPS;
        const int k = idx % NSTEPS + 1;
        const float th = thr[h];
        float beta = betap[0];
        beta = beta < 0.f ? 0.f : (beta > 1.f ? 1.f : beta);
        unsigned lo = f2k(-3.0e38f), hi = f2k(3.0e38f);
        float res;
        if (lif_count(k2f(hi), beta, th) < k) res = 3.0e38f;
        else if (lif_count(k2f(lo), beta, th) >= k) res = -3.0e38f;
        else {
#pragma unroll 1
            for (int it = 0; it < 32; it++) {
                unsigned mid = lo + ((hi - lo) >> 1);
                if (lif_count(k2f(mid), beta, th) >= k) hi = mid; else lo = mid;
            }
            res = k2f(hi);
        }
        bp[(k - 1) * NH + h] = res;
        return;
    }
    bid -= 100;
    const int i = bid * 256 + tid;
    if (i < B) out[i] = b2[0];
}

__global__ __launch_bounds__(256, 3) void snn_main_fb(
    const float* __restrict__ x, const float* __restrict__ W1,
    const float* __restrict__ b1, const float* __restrict__ W2,
    const float* __restrict__ bp, float* __restrict__ out)
{
    __shared__ __align__(16) _Float16 lds[4 * BT * RW];
    _Float16* xh = lds;
    _Float16* xl = lds + BT * RW;
    _Float16* wh = lds + 2 * BT * RW;
    _Float16* wl = lds + 3 * BT * RW;

    const int tid  = threadIdx.x;
    const int w    = tid >> 6;
    const int lane = tid & 63;
    const int col  = lane & 15;
    const int quad = lane >> 4;
    const int wbb  = (w >> 1) * 64;
    const int whh  = (w & 1) * 64;
    const int b0 = blockIdx.x * BT;
    const int h0 = blockIdx.y * BT;

    float4v acc[4][4];
#pragma unroll
    for (int i = 0; i < 4; i++)
#pragma unroll
        for (int j = 0; j < 4; j++) acc[i][j] = (float4v){0.f, 0.f, 0.f, 0.f};

    const int r0 = tid >> 3;
    const int c4 = tid & 7;
    const float* xrow = x + (size_t)(b0 + r0) * NI + 4 * c4;
    const float* wrow = W1 + (size_t)(h0 + r0) * NI + 4 * c4;

    for (int kt = 0; kt < NTILES; kt++) {
        const int ko = kt * BK;
        float4v vx[4], vw[4];
#pragma unroll
        for (int p = 0; p < 4; p++) {
            vx[p] = *(const float4v*)(xrow + (size_t)(32 * p) * NI + ko);
            vw[p] = *(const float4v*)(wrow + (size_t)(32 * p) * NI + ko);
        }
        __syncthreads();
#pragma unroll
        for (int p = 0; p < 4; p++) {
            const int row = r0 + 32 * p;
            half4 hx, lx, hw, lw;
#pragma unroll
            for (int q = 0; q < 4; q++) {
                float v = vx[p][q];
                _Float16 h = (_Float16)v;
                hx[q] = h;
                lx[q] = (_Float16)(v - (float)h);
                v = vw[p][q];
                h = (_Float16)v;
                hw[q] = h;
                lw[q] = (_Float16)(v - (float)h);
            }
            *(half4*)&xh[row * RW + 4 * c4] = hx;
            *(half4*)&xl[row * RW + 4 * c4] = lx;
            *(half4*)&wh[row * RW + 4 * c4] = hw;
            *(half4*)&wl[row * RW + 4 * c4] = lw;
        }
        __syncthreads();

        half8 ah[4], al[4];
#pragma unroll
        for (int i = 0; i < 4; i++) {
            ah[i] = *(const half8*)&xh[(wbb + 16 * i + col) * RW + 8 * quad];
            al[i] = *(const half8*)&xl[(wbb + 16 * i + col) * RW + 8 * quad];
        }
#pragma unroll
        for (int j = 0; j < 4; j++) {
            half8 bh = *(const half8*)&wh[(whh + 16 * j + col) * RW + 8 * quad];
            half8 bl = *(const half8*)&wl[(whh + 16 * j + col) * RW + 8 * quad];
#pragma unroll
            for (int i = 0; i < 4; i++) {
                acc[i][j] = __builtin_amdgcn_mfma_f32_16x16x32_f16(ah[i], bh, acc[i][j], 0, 0, 0);
                acc[i][j] = __builtin_amdgcn_mfma_f32_16x16x32_f16(ah[i], bl, acc[i][j], 0, 0, 0);
                acc[i][j] = __builtin_amdgcn_mfma_f32_16x16x32_f16(al[i], bh, acc[i][j], 0, 0, 0);
            }
        }
    }

    __syncthreads();
    float* bpl = (float*)lds;
    for (int n = tid; n < NSTEPS * 128; n += 256)
        bpl[n] = bp[(n >> 7) * NH + h0 + (n & 127)];
    __syncthreads();

    float part[16];
#pragma unroll
    for (int e = 0; e < 16; e++) part[e] = 0.f;
#pragma unroll
    for (int j = 0; j < 4; j++) {
        const int hl = whh + 16 * j + col;
        const int h = h0 + hl;
        const float w2 = W2[h];
        const float bj = b1[h];
        float x1[16];
        int cnt[16];
#pragma unroll
        for (int e = 0; e < 16; e++) {
            x1[e] = acc[e >> 2][j][e & 3] + bj;
            cnt[e] = 0;
        }
#pragma unroll
        for (int k = 0; k < NSTEPS; k++) {
            const float c = bpl[k * 128 + hl];
#pragma unroll
            for (int e = 0; e < 16; e++) cnt[e] += (x1[e] >= c) ? 1 : 0;
        }
#pragma unroll
        for (int e = 0; e < 16; e++)
            part[e] = fmaf((float)cnt[e], w2, part[e]);
    }

    __syncthreads();
    float* red = (float*)lds;
#pragma unroll
    for (int e = 0; e < 16; e++) {
        const int row = wbb + 16 * (e >> 2) + 4 * quad + (e & 3);
        red[row * 33 + (w & 1) * 16 + col] = part[e];
    }
    __syncthreads();
    if (tid < BT) {
        float s = 0.f;
#pragma unroll
        for (int c = 0; c < 32; c++) s += red[tid * 33 + c];
        atomicAdd(&out[b0 + tid], s);
    }
}

extern "C" void kernel_launch(void* const* d_in, const int* in_sizes, int n_in,
                              void* d_out, int out_size, void* d_ws, size_t ws_size,
                              hipStream_t stream) {
    const float* x    = (const float*)d_in[0];
    const float* W1   = (const float*)d_in[1];
    const float* b1   = (const float*)d_in[2];
    const float* W2   = (const float*)d_in[3];
    const float* b2   = (const float*)d_in[4];
    const float* beta = (const float*)d_in[5];
    const float* thr  = (const float*)d_in[6];
    float* out = (float*)d_out;

    const int B = in_sizes[0] / NI;  // 32768

    // ws layout: bp (NH*BPW floats) | wh | wl | xh
    char* ws = (char*)d_ws;
    float*     bp  = (float*)ws;
    size_t off = (size_t)NH * BPW * 4;               // 163840
    _Float16* whp = (_Float16*)(ws + off);  off += (size_t)NH * NI * 2;
    _Float16* wlp = (_Float16*)(ws + off);  off += (size_t)NH * NI * 2;
    _Float16* xhp = (_Float16*)(ws + off);  off += (size_t)B * NI * 2;
    const size_t ws_need = off;

    if (ws_size >= ws_need) {
        const int nblk = B / 8 + 128 + 100 + (B + 255) / 256;
        snn_prep<<<nblk, 256, 0, stream>>>(x, W1, thr, beta, b1, b2, W2, out,
                                           bp, whp, wlp, xhp, B);
        dim3 grid(B / BT, NH / BT);
        snn_main_fast<<<grid, 256, 0, stream>>>(xhp, whp, wlp, W2, bp, out);
    } else {
        snn_prep_small<<<100 + (B + 255) / 256, 256, 0, stream>>>(thr, beta, b2, out, bp, B);
        dim3 grid(B / BT, NH / BT);
        snn_main_fb<<<grid, 256, 0, stream>>>(x, W1, b1, W2, bp, out);
    }
}